// Round 1
// baseline (619.508 us; speedup 1.0000x reference)
//
#include <hip/hip_runtime.h>

#define D_STATE 64
#define L_SEQ   4096
#define D_MODEL 512
#define BATCH   4

// ---------------------------------------------------------------------------
// Kernel 1: precompute K[m] = c^T A^m b for m = 0..4095 (single block).
//   K[64q + r] = (c^T P^q) . (A^r b),  P = A^64.
// Phase 1: squaring chain A -> A^2 -> ... -> A^64 (6 LDS matmuls, 4x4 micro)
// Phase 2: vr[r] = A^r b (wave 0) and cq[q] = c^T P^q (wave 1), 64 steps,
//          per-lane row/column cached in VGPRs, results stored transposed
//          (state-major) in LDS for phase 3's vectorized reads.
// Phase 3: K = CQ * VR^T  (64x64x64 matmul, 4x4 micro, float4 LDS reads)
// ---------------------------------------------------------------------------
__global__ __launch_bounds__(256) void k_precompute(
    const float* __restrict__ A, const float* __restrict__ B,
    const float* __restrict__ C, float* __restrict__ Kker) {
  __shared__ float Ma[64][68];
  __shared__ float Mb[64][68];
  __shared__ float As[64][68];
  __shared__ float vrT[64][68];   // vrT[i][r] = (A^r b)[i]
  __shared__ float cqT[64][68];   // cqT[i][q] = (c^T P^q)[i]
  __shared__ __align__(16) float vcur[64];
  __shared__ __align__(16) float ccur[64];

  const int tid = threadIdx.x;

  // load A into Ma (squaring workspace) and As (preserved original)
  for (int e = tid; e < 4096; e += 256) {
    const int i = e >> 6, j = e & 63;
    const float a = A[e];
    Ma[i][j] = a;
    As[i][j] = a;
  }
  __syncthreads();

  // ---- Phase 1: P = A^64 via 6 squarings (ping-pong Ma <-> Mb) ----
  const int iy = tid >> 4, jx = tid & 15;
  const int iy4 = iy * 4, jx4 = jx * 4;
  for (int it = 0; it < 6; ++it) {
    float (*src)[68] = (it & 1) ? Mb : Ma;
    float (*dst)[68] = (it & 1) ? Ma : Mb;
    float acc[4][4] = {{0.f}};
#pragma unroll 8
    for (int k = 0; k < 64; ++k) {
      const float a0 = src[iy4 + 0][k];
      const float a1 = src[iy4 + 1][k];
      const float a2 = src[iy4 + 2][k];
      const float a3 = src[iy4 + 3][k];
      const float4 b4 = *(const float4*)&src[k][jx4];
      acc[0][0] += a0 * b4.x; acc[0][1] += a0 * b4.y; acc[0][2] += a0 * b4.z; acc[0][3] += a0 * b4.w;
      acc[1][0] += a1 * b4.x; acc[1][1] += a1 * b4.y; acc[1][2] += a1 * b4.z; acc[1][3] += a1 * b4.w;
      acc[2][0] += a2 * b4.x; acc[2][1] += a2 * b4.y; acc[2][2] += a2 * b4.z; acc[2][3] += a2 * b4.w;
      acc[3][0] += a3 * b4.x; acc[3][1] += a3 * b4.y; acc[3][2] += a3 * b4.z; acc[3][3] += a3 * b4.w;
    }
#pragma unroll
    for (int r = 0; r < 4; ++r)
#pragma unroll
      for (int c = 0; c < 4; ++c) dst[iy4 + r][jx4 + c] = acc[r][c];
    __syncthreads();
  }
  // P now lives in Ma (iterations 1,3,5 wrote Ma; last write was it=5 -> Ma).

  // ---- Phase 2: vr chain (wave 0) and cq chain (wave 1) ----
  float row[64];
  if (tid < 64) {
#pragma unroll
    for (int j = 0; j < 64; ++j) row[j] = As[tid][j];  // A row tid
    vcur[tid] = B[tid];
    vrT[tid][0] = B[tid];
  } else if (tid < 128) {
    const int i = tid - 64;
#pragma unroll
    for (int j = 0; j < 64; ++j) row[j] = Ma[j][i];    // P column i
    ccur[i] = C[i];
    cqT[i][0] = C[i];
  }
  __syncthreads();

  for (int stp = 1; stp < 64; ++stp) {
    float nv = 0.f;
    if (tid < 128) {
      const float* sv = (tid < 64) ? vcur : ccur;
      float a0 = 0.f, a1 = 0.f, a2 = 0.f, a3 = 0.f;
#pragma unroll
      for (int j = 0; j < 64; j += 4) {
        const float4 x = *(const float4*)&sv[j];
        a0 += row[j + 0] * x.x;
        a1 += row[j + 1] * x.y;
        a2 += row[j + 2] * x.z;
        a3 += row[j + 3] * x.w;
      }
      nv = (a0 + a1) + (a2 + a3);
    }
    __syncthreads();  // everyone done reading vcur/ccur
    if (tid < 64) {
      vcur[tid] = nv;
      vrT[tid][stp] = nv;
    } else if (tid < 128) {
      const int i = tid - 64;
      ccur[i] = nv;
      cqT[i][stp] = nv;
    }
    __syncthreads();
  }

  // ---- Phase 3: K[q*64 + r] = sum_i cqT[i][q] * vrT[i][r] ----
  {
    float acc[4][4] = {{0.f}};
    const int qy4 = iy4, rx4 = jx4;  // q-rows, r-cols
#pragma unroll 8
    for (int i = 0; i < 64; ++i) {
      const float4 a4 = *(const float4*)&cqT[i][qy4];
      const float4 b4 = *(const float4*)&vrT[i][rx4];
      acc[0][0] += a4.x * b4.x; acc[0][1] += a4.x * b4.y; acc[0][2] += a4.x * b4.z; acc[0][3] += a4.x * b4.w;
      acc[1][0] += a4.y * b4.x; acc[1][1] += a4.y * b4.y; acc[1][2] += a4.y * b4.z; acc[1][3] += a4.y * b4.w;
      acc[2][0] += a4.z * b4.x; acc[2][1] += a4.z * b4.y; acc[2][2] += a4.z * b4.z; acc[2][3] += a4.z * b4.w;
      acc[3][0] += a4.w * b4.x; acc[3][1] += a4.w * b4.y; acc[3][2] += a4.w * b4.z; acc[3][3] += a4.w * b4.w;
    }
#pragma unroll
    for (int r = 0; r < 4; ++r) {
      float4 v;
      v.x = acc[r][0]; v.y = acc[r][1]; v.z = acc[r][2]; v.w = acc[r][3];
      *(float4*)&Kker[(qy4 + r) * 64 + rx4] = v;
    }
  }
}

// ---------------------------------------------------------------------------
// Kernel 2: y[t, s] = sum_{t'<=t} K[t-t'] * u[t', s]
// Lower-triangular Toeplitz (4096x4096, built on the fly from K) times
// U (4096 x 2048). 64x64 output tiles, BK=64, 4x4 register micro-tiles.
// Row block tr only iterates tr+1 k-tiles (upper triangle skipped);
// masking (idx<0 -> 0) only ever fires on the diagonal tile.
// Memory layout: u/out flat index = ((b*4096 + t) * 512 + d), s = b*512 + d.
// ---------------------------------------------------------------------------
__global__ __launch_bounds__(256) void k_conv(
    const float* __restrict__ u, const float* __restrict__ Kker,
    float* __restrict__ out) {
  __shared__ float As[64][68];  // As[kk][i] = T[t0+i, k0+kk]
  __shared__ float Us[64][68];  // Us[kk][j] = U[k0+kk, s0+j]

  const int sg = blockIdx.x;                       // sequence group (0..31)
  const int tr = (int)(gridDim.y - 1) - (int)blockIdx.y;  // heavy rows first
  const int t0 = tr * 64;
  const int s0 = sg * 64;
  const int b = s0 >> 9;        // batch
  const int d0 = s0 & 511;      // d offset (multiple of 64 -> aligned)

  const float* __restrict__ ub = u + (size_t)b * L_SEQ * D_MODEL + d0;
  float* __restrict__ ob = out + (size_t)b * L_SEQ * D_MODEL + d0;

  const int tid = threadIdx.x;
  const int ty = tid >> 4, tx = tid & 15;
  const int ty4 = ty * 4, tx4 = tx * 4;

  float acc[4][4] = {{0.f}};

  const int nk = tr + 1;
  for (int kt = 0; kt < nk; ++kt) {
    const int k0 = kt * 64;
    const int diff0 = t0 - k0;  // >= 0, multiple of 64

    // stage U tile (coalesced float4 rows)
    for (int e = tid; e < 64 * 16; e += 256) {
      const int kk = e >> 4, j4 = (e & 15) * 4;
      *(float4*)&Us[kk][j4] =
          *(const float4*)&ub[(size_t)(k0 + kk) * D_MODEL + j4];
    }
    // stage Toeplitz tile from K (L1-resident, coalesced along i)
    for (int e = tid; e < 64 * 64; e += 256) {
      const int kk = e >> 6, i = e & 63;
      const int idx = diff0 + i - kk;  // <= 4095 always
      As[kk][i] = (idx >= 0) ? Kker[idx] : 0.f;
    }
    __syncthreads();

#pragma unroll 8
    for (int kk = 0; kk < 64; ++kk) {
      const float4 a4 = *(const float4*)&As[kk][ty4];
      const float4 b4 = *(const float4*)&Us[kk][tx4];
      acc[0][0] += a4.x * b4.x; acc[0][1] += a4.x * b4.y; acc[0][2] += a4.x * b4.z; acc[0][3] += a4.x * b4.w;
      acc[1][0] += a4.y * b4.x; acc[1][1] += a4.y * b4.y; acc[1][2] += a4.y * b4.z; acc[1][3] += a4.y * b4.w;
      acc[2][0] += a4.z * b4.x; acc[2][1] += a4.z * b4.y; acc[2][2] += a4.z * b4.z; acc[2][3] += a4.z * b4.w;
      acc[3][0] += a4.w * b4.x; acc[3][1] += a4.w * b4.y; acc[3][2] += a4.w * b4.z; acc[3][3] += a4.w * b4.w;
    }
    __syncthreads();
  }

#pragma unroll
  for (int r = 0; r < 4; ++r) {
    float4 v;
    v.x = acc[r][0]; v.y = acc[r][1]; v.z = acc[r][2]; v.w = acc[r][3];
    *(float4*)&ob[(size_t)(t0 + ty4 + r) * D_MODEL + tx4] = v;
  }
}

extern "C" void kernel_launch(void* const* d_in, const int* in_sizes, int n_in,
                              void* d_out, int out_size, void* d_ws,
                              size_t ws_size, hipStream_t stream) {
  const float* u = (const float*)d_in[0];   // (4, 4096, 512) f32
  const float* A = (const float*)d_in[1];   // (64, 64) f32
  const float* B = (const float*)d_in[2];   // (64, 1) f32
  const float* C = (const float*)d_in[3];   // (1, 64) f32
  float* out = (float*)d_out;               // (4, 4096, 512) f32
  float* Kker = (float*)d_ws;               // 4096 floats (16 KB)

  k_precompute<<<1, 256, 0, stream>>>(A, B, C, Kker);
  k_conv<<<dim3(32, 64), 256, 0, stream>>>(u, Kker, out);
}

// Round 2
// 301.854 us; speedup vs baseline: 2.0523x; 2.0523x over previous
//
#include <hip/hip_runtime.h>
#include <hip/hip_fp16.h>

#define D_STATE 64
#define L_SEQ   4096
#define D_MODEL 512
#define BATCH   4

typedef _Float16 half8 __attribute__((ext_vector_type(8)));
typedef float f32x4 __attribute__((ext_vector_type(4)));

// Kr tables: Kr[i] = K[4095-i] for i<=4095, 0 for 4096..4351 (guard for the
// diagonal/partial tiles). Stored as f16 hi + f16 lo with hi+lo ~= fp32 K.
#define KR_LEN 4352
#define KR_BYTES (KR_LEN * 2)          // 8704 B per table
#define UPK_BYTES ((size_t)64 * 2048 * 64 * 2)  // 16 MiB per table

// ===========================================================================
// Kernel 1 (f16 path): compute K[m] = c^T A^m b, emit reversed split tables.
// Phase 1: P = A^64 via 6 LDS squarings (256 thr).
// Phase 2: vr_r = A^r b (wave 0) and cq_q = c^T P^q (wave 1), 64 steps each,
//          barrier-free inside a wave using v_readlane broadcasts.
// Phase 3: K = CQ * VR^T outer-product matmul; write Kr_hi/Kr_lo reversed.
// ===========================================================================
__global__ __launch_bounds__(256) void k_prep_f16(
    const float* __restrict__ A, const float* __restrict__ B,
    const float* __restrict__ C, __half* __restrict__ Kr_hi,
    __half* __restrict__ Kr_lo) {
  __shared__ float Ma[64][68];
  __shared__ float Mb[64][68];
  __shared__ float As[64][68];
  __shared__ float vrT[64][68];   // vrT[i][r] = (A^r b)[i]
  __shared__ float cqT[64][68];   // cqT[i][q] = (c^T P^q)[i]

  const int tid = threadIdx.x;

  // zero guard tail of Kr tables (4096..4351)
  Kr_hi[4096 + tid] = (__half)0.0f;
  Kr_lo[4096 + tid] = (__half)0.0f;

  for (int e = tid; e < 4096; e += 256) {
    const int i = e >> 6, j = e & 63;
    const float a = A[e];
    Ma[i][j] = a;
    As[i][j] = a;
  }
  __syncthreads();

  // ---- Phase 1: P = A^64 (ping-pong Ma <-> Mb; ends in Ma) ----
  const int iy = tid >> 4, jx = tid & 15;
  const int iy4 = iy * 4, jx4 = jx * 4;
  for (int it = 0; it < 6; ++it) {
    float (*src)[68] = (it & 1) ? Mb : Ma;
    float (*dst)[68] = (it & 1) ? Ma : Mb;
    float acc[4][4] = {{0.f}};
#pragma unroll 8
    for (int k = 0; k < 64; ++k) {
      const float a0 = src[iy4 + 0][k];
      const float a1 = src[iy4 + 1][k];
      const float a2 = src[iy4 + 2][k];
      const float a3 = src[iy4 + 3][k];
      const float4 b4 = *(const float4*)&src[k][jx4];
      acc[0][0] += a0 * b4.x; acc[0][1] += a0 * b4.y; acc[0][2] += a0 * b4.z; acc[0][3] += a0 * b4.w;
      acc[1][0] += a1 * b4.x; acc[1][1] += a1 * b4.y; acc[1][2] += a1 * b4.z; acc[1][3] += a1 * b4.w;
      acc[2][0] += a2 * b4.x; acc[2][1] += a2 * b4.y; acc[2][2] += a2 * b4.z; acc[2][3] += a2 * b4.w;
      acc[3][0] += a3 * b4.x; acc[3][1] += a3 * b4.y; acc[3][2] += a3 * b4.z; acc[3][3] += a3 * b4.w;
    }
#pragma unroll
    for (int r = 0; r < 4; ++r)
#pragma unroll
      for (int c = 0; c < 4; ++c) dst[iy4 + r][jx4 + c] = acc[r][c];
    __syncthreads();
  }

  // ---- Phase 2: barrier-free chains in waves 0 and 1 ----
  const int lane = tid & 63;
  const int wave = tid >> 6;
  if (wave < 2) {
    float reg[64];
    float cur;
    if (wave == 0) {
#pragma unroll
      for (int j = 0; j < 64; ++j) reg[j] = As[lane][j];  // A row
      cur = B[lane];
      vrT[lane][0] = cur;
    } else {
#pragma unroll
      for (int j = 0; j < 64; ++j) reg[j] = Ma[j][lane];  // P column
      cur = C[lane];
      cqT[lane][0] = cur;
    }
    for (int stp = 1; stp < 64; ++stp) {
      float nv = 0.f;
#pragma unroll
      for (int j = 0; j < 64; ++j) {
        const float bj =
            __int_as_float(__builtin_amdgcn_readlane(__float_as_int(cur), j));
        nv += reg[j] * bj;
      }
      cur = nv;
      if (wave == 0) vrT[lane][stp] = cur;
      else           cqT[lane][stp] = cur;
    }
  }
  __syncthreads();

  // ---- Phase 3: K[q*64+r] = sum_i cqT[i][q]*vrT[i][r]; write reversed f16 ----
  {
    float acc[4][4] = {{0.f}};
#pragma unroll 8
    for (int i = 0; i < 64; ++i) {
      const float4 a4 = *(const float4*)&cqT[i][iy4];
      const float4 b4 = *(const float4*)&vrT[i][jx4];
      acc[0][0] += a4.x * b4.x; acc[0][1] += a4.x * b4.y; acc[0][2] += a4.x * b4.z; acc[0][3] += a4.x * b4.w;
      acc[1][0] += a4.y * b4.x; acc[1][1] += a4.y * b4.y; acc[1][2] += a4.y * b4.z; acc[1][3] += a4.y * b4.w;
      acc[2][0] += a4.z * b4.x; acc[2][1] += a4.z * b4.y; acc[2][2] += a4.z * b4.z; acc[2][3] += a4.z * b4.w;
      acc[3][0] += a4.w * b4.x; acc[3][1] += a4.w * b4.y; acc[3][2] += a4.w * b4.z; acc[3][3] += a4.w * b4.w;
    }
#pragma unroll
    for (int r = 0; r < 4; ++r)
#pragma unroll
      for (int c = 0; c < 4; ++c) {
        const int m = (iy4 + r) * 64 + jx4 + c;
        const float v = acc[r][c];
        const _Float16 hh = (_Float16)v;
        const _Float16 ll = (_Float16)(v - (float)hh);
        Kr_hi[4095 - m] = *(const __half*)&hh;
        Kr_lo[4095 - m] = *(const __half*)&ll;
      }
  }
}

// ===========================================================================
// Kernel 2 (f16 path): split u into f16 hi/lo and transpose into the packed
// layout Upk[kt][s][kk] (kt = t/64, kk = t%64, s = b*512+d) so conv staging
// is a dense contiguous copy in the exact LDS order needed (k-inner).
// ===========================================================================
__global__ __launch_bounds__(256) void k_usplit(
    const float* __restrict__ u, __half* __restrict__ Upk_hi,
    __half* __restrict__ Upk_lo) {
  __shared__ __align__(16) float Ut[64][68];
  const int tt = blockIdx.x;   // t-tile 0..63
  const int sb = blockIdx.y;   // s-tile 0..31
  const int tid = threadIdx.x;
  const int s0 = sb * 64;
  const int b = s0 >> 9;
  const int d0 = s0 & 511;
  const float* ub = u + ((size_t)b * L_SEQ + tt * 64) * D_MODEL + d0;

#pragma unroll
  for (int i = 0; i < 4; ++i) {
    const int c = tid + 256 * i;      // 1024 float4 chunks (64 rows x 16)
    const int row = c >> 4, c4 = (c & 15) * 4;
    *(float4*)&Ut[row][c4] = *(const float4*)(ub + (size_t)row * D_MODEL + c4);
  }
  __syncthreads();

  const int s_l = tid & 63;
  const int wv = tid >> 6;
#pragma unroll
  for (int i = 0; i < 2; ++i) {
    const int k8 = wv + i * 4;        // 8-half chunk index within the 64 k's
    half8 h, l;
#pragma unroll
    for (int j = 0; j < 8; ++j) {
      const float x = Ut[k8 * 8 + j][s_l];
      const _Float16 hh = (_Float16)x;
      h[j] = hh;
      l[j] = (_Float16)(x - (float)hh);
    }
    const size_t off = ((size_t)tt * 2048 + (s0 + s_l)) * 64 + k8 * 8;
    *(half8*)(Upk_hi + off) = h;
    *(half8*)(Upk_lo + off) = l;
  }
}

// ===========================================================================
// Kernel 3 (f16 path): y = T * U via split-f16 MFMA.
// 128x128 output tile, BK=64, 4 waves of 64x64 (4x4 frags of 16x16x32).
// A-fragments come straight from the L1-resident reversed Kr tables
// (per-lane 16B loads, zero-guarded so no masking is ever needed).
// B-fragments from LDS Bs[s][k] (+8-half pad -> 2-way conflicts only).
// 3 MFMA passes per frag: hi*hi + hi*lo + lo*hi  (~fp32 precision).
// ===========================================================================
__global__ __launch_bounds__(256) void k_conv_f16(
    const __half* __restrict__ Upk_hi, const __half* __restrict__ Upk_lo,
    const __half* __restrict__ Kr_hi, const __half* __restrict__ Kr_lo,
    float* __restrict__ out) {
  __shared__ __align__(16) __half Bs_hi[128][72];
  __shared__ __align__(16) __half Bs_lo[128][72];

  const int bid = blockIdx.x;
  const int tr = 31 - (bid >> 4);   // heavy rows first
  const int sg = bid & 15;
  const int t0 = tr * 128;
  const int s0 = sg * 128;

  const int tid = threadIdx.x;
  const int lane = tid & 63;
  const int wave = tid >> 6;
  const int wr = (wave >> 1) * 64;  // wave row offset in tile
  const int wc = (wave & 1) * 64;   // wave col offset in tile
  const int lid = lane & 15;
  const int quad = lane >> 4;

  f32x4 acc[4][4];
#pragma unroll
  for (int a = 0; a < 4; ++a)
#pragma unroll
    for (int bq = 0; bq < 4; ++bq) acc[a][bq] = (f32x4)(0.f);

  const int nk = 2 * (tr + 1);
  for (int kt = 0; kt < nk; ++kt) {
    const int kbase = kt * 64;
    const __half* src_hi = Upk_hi + ((size_t)kt * 2048 + s0) * 64;
    const __half* src_lo = Upk_lo + ((size_t)kt * 2048 + s0) * 64;
#pragma unroll
    for (int i = 0; i < 4; ++i) {
      const int c = tid + 256 * i;  // 1024 chunks of 8 halves
      const int row = c >> 3, c8 = (c & 7) * 8;
      *(half8*)&Bs_hi[row][c8] = *(const half8*)(src_hi + (size_t)c * 8);
      *(half8*)&Bs_lo[row][c8] = *(const half8*)(src_lo + (size_t)c * 8);
    }
    __syncthreads();

    const int g0 = 4095 - t0 + kbase;
#pragma unroll
    for (int step = 0; step < 2; ++step) {
      const int kq = step * 32 + quad * 8;
      half8 ah[4], al[4], bh[4], bl[4];
#pragma unroll
      for (int f = 0; f < 4; ++f) {
        const int srow = wc + f * 16 + lid;
        bh[f] = *(const half8*)&Bs_hi[srow][kq];
        bl[f] = *(const half8*)&Bs_lo[srow][kq];
        const int idx = g0 - (wr + f * 16 + lid) + kq;  // in [0, 4223]
        __builtin_memcpy(&ah[f], Kr_hi + idx, 16);      // unaligned 16B ok
        __builtin_memcpy(&al[f], Kr_lo + idx, 16);
      }
#pragma unroll
      for (int im = 0; im < 4; ++im)
#pragma unroll
        for (int in = 0; in < 4; ++in) {
          acc[im][in] = __builtin_amdgcn_mfma_f32_16x16x32_f16(
              ah[im], bh[in], acc[im][in], 0, 0, 0);
          acc[im][in] = __builtin_amdgcn_mfma_f32_16x16x32_f16(
              ah[im], bl[in], acc[im][in], 0, 0, 0);
          acc[im][in] = __builtin_amdgcn_mfma_f32_16x16x32_f16(
              al[im], bh[in], acc[im][in], 0, 0, 0);
        }
    }
    __syncthreads();
  }

#pragma unroll
  for (int im = 0; im < 4; ++im)
#pragma unroll
    for (int in = 0; in < 4; ++in) {
      const int s = s0 + wc + in * 16 + lid;
      const int bi = s >> 9, d = s & 511;
      float* op = out + ((size_t)bi * L_SEQ) * D_MODEL + d;
#pragma unroll
      for (int r = 0; r < 4; ++r) {
        const int row = t0 + wr + im * 16 + quad * 4 + r;
        op[(size_t)row * D_MODEL] = acc[im][in][r];
      }
    }
}

// ===========================================================================
// Fallback fp32 path (round-1 kernels, used only if ws is too small)
// ===========================================================================
__global__ __launch_bounds__(256) void k_precompute_f32(
    const float* __restrict__ A, const float* __restrict__ B,
    const float* __restrict__ C, float* __restrict__ Kker) {
  __shared__ float Ma[64][68];
  __shared__ float Mb[64][68];
  __shared__ float As[64][68];
  __shared__ float vrT[64][68];
  __shared__ float cqT[64][68];
  __shared__ __align__(16) float vcur[64];
  __shared__ __align__(16) float ccur[64];

  const int tid = threadIdx.x;
  for (int e = tid; e < 4096; e += 256) {
    const int i = e >> 6, j = e & 63;
    const float a = A[e];
    Ma[i][j] = a;
    As[i][j] = a;
  }
  __syncthreads();
  const int iy = tid >> 4, jx = tid & 15;
  const int iy4 = iy * 4, jx4 = jx * 4;
  for (int it = 0; it < 6; ++it) {
    float (*src)[68] = (it & 1) ? Mb : Ma;
    float (*dst)[68] = (it & 1) ? Ma : Mb;
    float acc[4][4] = {{0.f}};
#pragma unroll 8
    for (int k = 0; k < 64; ++k) {
      const float a0 = src[iy4 + 0][k];
      const float a1 = src[iy4 + 1][k];
      const float a2 = src[iy4 + 2][k];
      const float a3 = src[iy4 + 3][k];
      const float4 b4 = *(const float4*)&src[k][jx4];
      acc[0][0] += a0 * b4.x; acc[0][1] += a0 * b4.y; acc[0][2] += a0 * b4.z; acc[0][3] += a0 * b4.w;
      acc[1][0] += a1 * b4.x; acc[1][1] += a1 * b4.y; acc[1][2] += a1 * b4.z; acc[1][3] += a1 * b4.w;
      acc[2][0] += a2 * b4.x; acc[2][1] += a2 * b4.y; acc[2][2] += a2 * b4.z; acc[2][3] += a2 * b4.w;
      acc[3][0] += a3 * b4.x; acc[3][1] += a3 * b4.y; acc[3][2] += a3 * b4.z; acc[3][3] += a3 * b4.w;
    }
#pragma unroll
    for (int r = 0; r < 4; ++r)
#pragma unroll
      for (int c = 0; c < 4; ++c) dst[iy4 + r][jx4 + c] = acc[r][c];
    __syncthreads();
  }
  float row[64];
  if (tid < 64) {
#pragma unroll
    for (int j = 0; j < 64; ++j) row[j] = As[tid][j];
    vcur[tid] = B[tid];
    vrT[tid][0] = B[tid];
  } else if (tid < 128) {
    const int i = tid - 64;
#pragma unroll
    for (int j = 0; j < 64; ++j) row[j] = Ma[j][i];
    ccur[i] = C[i];
    cqT[i][0] = C[i];
  }
  __syncthreads();
  for (int stp = 1; stp < 64; ++stp) {
    float nv = 0.f;
    if (tid < 128) {
      const float* sv = (tid < 64) ? vcur : ccur;
      float a0 = 0.f, a1 = 0.f, a2 = 0.f, a3 = 0.f;
#pragma unroll
      for (int j = 0; j < 64; j += 4) {
        const float4 x = *(const float4*)&sv[j];
        a0 += row[j + 0] * x.x;
        a1 += row[j + 1] * x.y;
        a2 += row[j + 2] * x.z;
        a3 += row[j + 3] * x.w;
      }
      nv = (a0 + a1) + (a2 + a3);
    }
    __syncthreads();
    if (tid < 64) {
      vcur[tid] = nv;
      vrT[tid][stp] = nv;
    } else if (tid < 128) {
      const int i = tid - 64;
      ccur[i] = nv;
      cqT[i][stp] = nv;
    }
    __syncthreads();
  }
  {
    float acc[4][4] = {{0.f}};
#pragma unroll 8
    for (int i = 0; i < 64; ++i) {
      const float4 a4 = *(const float4*)&cqT[i][iy4];
      const float4 b4 = *(const float4*)&vrT[i][jx4];
      acc[0][0] += a4.x * b4.x; acc[0][1] += a4.x * b4.y; acc[0][2] += a4.x * b4.z; acc[0][3] += a4.x * b4.w;
      acc[1][0] += a4.y * b4.x; acc[1][1] += a4.y * b4.y; acc[1][2] += a4.y * b4.z; acc[1][3] += a4.y * b4.w;
      acc[2][0] += a4.z * b4.x; acc[2][1] += a4.z * b4.y; acc[2][2] += a4.z * b4.z; acc[2][3] += a4.z * b4.w;
      acc[3][0] += a4.w * b4.x; acc[3][1] += a4.w * b4.y; acc[3][2] += a4.w * b4.z; acc[3][3] += a4.w * b4.w;
    }
#pragma unroll
    for (int r = 0; r < 4; ++r) {
      float4 v;
      v.x = acc[r][0]; v.y = acc[r][1]; v.z = acc[r][2]; v.w = acc[r][3];
      *(float4*)&Kker[(iy4 + r) * 64 + jx4] = v;
    }
  }
}

__global__ __launch_bounds__(256) void k_conv_f32(
    const float* __restrict__ u, const float* __restrict__ Kker,
    float* __restrict__ out) {
  __shared__ float As2[64][68];
  __shared__ float Us[64][68];
  const int sg = blockIdx.x;
  const int tr = (int)(gridDim.y - 1) - (int)blockIdx.y;
  const int t0 = tr * 64;
  const int s0 = sg * 64;
  const int b = s0 >> 9;
  const int d0 = s0 & 511;
  const float* __restrict__ ub = u + (size_t)b * L_SEQ * D_MODEL + d0;
  float* __restrict__ ob = out + (size_t)b * L_SEQ * D_MODEL + d0;
  const int tid = threadIdx.x;
  const int ty = tid >> 4, tx = tid & 15;
  const int ty4 = ty * 4, tx4 = tx * 4;
  float acc[4][4] = {{0.f}};
  const int nk = tr + 1;
  for (int kt = 0; kt < nk; ++kt) {
    const int k0 = kt * 64;
    const int diff0 = t0 - k0;
    for (int e = tid; e < 64 * 16; e += 256) {
      const int kk = e >> 4, j4 = (e & 15) * 4;
      *(float4*)&Us[kk][j4] =
          *(const float4*)&ub[(size_t)(k0 + kk) * D_MODEL + j4];
    }
    for (int e = tid; e < 64 * 64; e += 256) {
      const int kk = e >> 6, i = e & 63;
      const int idx = diff0 + i - kk;
      As2[kk][i] = (idx >= 0) ? Kker[idx] : 0.f;
    }
    __syncthreads();
#pragma unroll 8
    for (int kk = 0; kk < 64; ++kk) {
      const float4 a4 = *(const float4*)&As2[kk][ty4];
      const float4 b4 = *(const float4*)&Us[kk][tx4];
      acc[0][0] += a4.x * b4.x; acc[0][1] += a4.x * b4.y; acc[0][2] += a4.x * b4.z; acc[0][3] += a4.x * b4.w;
      acc[1][0] += a4.y * b4.x; acc[1][1] += a4.y * b4.y; acc[1][2] += a4.y * b4.z; acc[1][3] += a4.y * b4.w;
      acc[2][0] += a4.z * b4.x; acc[2][1] += a4.z * b4.y; acc[2][2] += a4.z * b4.z; acc[2][3] += a4.z * b4.w;
      acc[3][0] += a4.w * b4.x; acc[3][1] += a4.w * b4.y; acc[3][2] += a4.w * b4.z; acc[3][3] += a4.w * b4.w;
    }
    __syncthreads();
  }
#pragma unroll
  for (int r = 0; r < 4; ++r) {
    float4 v;
    v.x = acc[r][0]; v.y = acc[r][1]; v.z = acc[r][2]; v.w = acc[r][3];
    *(float4*)&ob[(size_t)(t0 + ty4 + r) * D_MODEL + tx4] = v;
  }
}

extern "C" void kernel_launch(void* const* d_in, const int* in_sizes, int n_in,
                              void* d_out, int out_size, void* d_ws,
                              size_t ws_size, hipStream_t stream) {
  const float* u = (const float*)d_in[0];
  const float* A = (const float*)d_in[1];
  const float* B = (const float*)d_in[2];
  const float* C = (const float*)d_in[3];
  float* out = (float*)d_out;

  const size_t need = 2 * KR_BYTES + 2 * UPK_BYTES;  // ~33.6 MB
  if (ws_size >= need) {
    __half* Kr_hi = (__half*)d_ws;
    __half* Kr_lo = (__half*)((char*)d_ws + KR_BYTES);
    __half* Upk_hi = (__half*)((char*)d_ws + 2 * KR_BYTES);
    __half* Upk_lo = (__half*)((char*)d_ws + 2 * KR_BYTES + UPK_BYTES);
    k_prep_f16<<<1, 256, 0, stream>>>(A, B, C, Kr_hi, Kr_lo);
    k_usplit<<<dim3(64, 32), 256, 0, stream>>>(u, Upk_hi, Upk_lo);
    k_conv_f16<<<512, 256, 0, stream>>>(Upk_hi, Upk_lo, Kr_hi, Kr_lo, out);
  } else {
    float* Kker = (float*)d_ws;
    k_precompute_f32<<<1, 256, 0, stream>>>(A, B, C, Kker);
    k_conv_f32<<<dim3(32, 64), 256, 0, stream>>>(u, Kker, out);
  }
}